// Round 1
// baseline (229.166 us; speedup 1.0000x reference)
//
#include <hip/hip_runtime.h>
#include <stdint.h>

#define N_NODES 30000
#define NC 256

typedef _Float16 f16x8 __attribute__((ext_vector_type(8)));
typedef _Float16 f16x4 __attribute__((ext_vector_type(4)));
typedef _Float16 f16x2 __attribute__((ext_vector_type(2)));
typedef float f32x4 __attribute__((ext_vector_type(4)));

// ---- convert x (with clip +-10) to f16 ----
__global__ void k_conv_x(const float* __restrict__ x, _Float16* __restrict__ xb) {
    int i = (blockIdx.x * 256 + threadIdx.x) * 4;   // total 7,680,000 -> 7500 blocks
    float4 v = *reinterpret_cast<const float4*>(x + i);
    f16x4 o;
    o[0] = (_Float16)fminf(fmaxf(v.x, -10.f), 10.f);
    o[1] = (_Float16)fminf(fmaxf(v.y, -10.f), 10.f);
    o[2] = (_Float16)fminf(fmaxf(v.z, -10.f), 10.f);
    o[3] = (_Float16)fminf(fmaxf(v.w, -10.f), 10.f);
    *reinterpret_cast<f16x4*>(xb + i) = o;
}

// ---- convert W = [w_real; w_imag] ([512][256]) to f16 ----
__global__ void k_conv_w(const float* __restrict__ wr, const float* __restrict__ wi,
                         _Float16* __restrict__ Wb) {
    int i = (blockIdx.x * 256 + threadIdx.x) * 4;   // total 131,072 -> 128 blocks
    const float* src = (i < NC * NC) ? (wr + i) : (wi + (i - NC * NC));
    float4 v = *reinterpret_cast<const float4*>(src);
    f16x4 o;
    o[0] = (_Float16)v.x; o[1] = (_Float16)v.y;
    o[2] = (_Float16)v.z; o[3] = (_Float16)v.w;
    *reinterpret_cast<f16x4*>(Wb + i) = o;
}

// ---- GEMM v4: A register-resident for full K; cn moved to block dim ----
// R5: 470 blocks x 4 waves = 1880 waves = 23% occupancy ceiling (230 VGPR ->
// 2 waves/SIMD). Splitting cn to blockIdx doubles resident waves (46% ceiling)
// to hide the B-load latency chain; A panel (15 MB f16) is L3-resident so the
// extra A re-fetch is cheap. Math identical to v3.
__global__ __launch_bounds__(256, 2) void k_gemm(
    const _Float16* __restrict__ A, const _Float16* __restrict__ B,
    const float* __restrict__ br, const float* __restrict__ bi,
    _Float16* __restrict__ H)
{
    int bid = blockIdx.x;
    int bm = bid >> 2, cs = (bid >> 1) & 1, cn = bid & 1;   // 235 x 2 x 2 blocks
    int tid = threadIdx.x;
    int lane = tid & 63, wave = tid >> 6;
    int quad = lane >> 4, l16 = lane & 15;
    int wm = wave >> 1, wn = wave & 1;        // wm: row half, wn: re/im
    int row0 = bm * 128 + wm * 64;

    f16x8 af[4][8];
#pragma unroll
    for (int mi = 0; mi < 4; mi++) {
        int r = row0 + mi * 16 + l16;
        if (r >= N_NODES) r = N_NODES - 1;    // clamp: garbage rows never stored
        const _Float16* ap = A + r * NC + quad * 8;
#pragma unroll
        for (int kc = 0; kc < 8; kc++)
            af[mi][kc] = *reinterpret_cast<const f16x8*>(ap + kc * 32);
    }

    const float* bias_p = wn ? bi : br;
    const _Float16* bbase = B + ((wn ? 256 : 0) + cs * 128 + cn * 64 + l16) * NC
                              + quad * 8;
    f16x8 bb[2][4];
#pragma unroll
    for (int ni = 0; ni < 4; ni++)
        bb[0][ni] = *reinterpret_cast<const f16x8*>(bbase + ni * 16 * NC);
    f32x4 acc[4][4] = {};
#pragma unroll
    for (int kc = 0; kc < 8; kc++) {
        int cur = kc & 1, nxt = cur ^ 1;
        if (kc < 7) {
#pragma unroll
            for (int ni = 0; ni < 4; ni++)
                bb[nxt][ni] = *reinterpret_cast<const f16x8*>(
                    bbase + ni * 16 * NC + (kc + 1) * 32);
        }
#pragma unroll
        for (int mi = 0; mi < 4; mi++)
#pragma unroll
            for (int ni = 0; ni < 4; ni++)
                acc[mi][ni] = __builtin_amdgcn_mfma_f32_16x16x32_f16(
                    af[mi][kc], bb[cur][ni], acc[mi][ni], 0, 0, 0);
    }
#pragma unroll
    for (int ni = 0; ni < 4; ni++) {
        int c = cs * 128 + cn * 64 + ni * 16 + l16;
        float bias = bias_p[c];
        int cc = 2 * c + wn;
#pragma unroll
        for (int mi = 0; mi < 4; mi++) {
            int rowb = row0 + mi * 16 + quad * 4;
#pragma unroll
            for (int r = 0; r < 4; r++) {
                int row = rowb + r;
                if (row < N_NODES)
                    H[row * 512 + cc] = (_Float16)(acc[mi][ni][r] + bias);
            }
        }
    }
}

// ---- evolve v3: 4 channels/lane, 16B loads; NPB 30->15 for occupancy ----
// R5 counters: dur 47.3us, HBM 28%, VALUBusy 16%, Occ 28% -> latency-bound.
// Root cause: grid 1000 x 4 waves = 4000 waves vs 8192 slots (48.8% ceiling,
// 28% observed). NPB=15 / 2000 blocks -> 8000 waves = 97.6% ceiling; per-node
// work, LDS layout and reduction unchanged. BW floor is ~104 MB -> 16.5 us.
#define NPB 15
__global__ __launch_bounds__(256) void k_evolve(
    const float* __restrict__ x, const int* __restrict__ sub_nodes,
    const float* __restrict__ sub_mask, const float* __restrict__ subH,
    const _Float16* __restrict__ h, const float* __restrict__ escp,
    float* __restrict__ outz, _Float16* __restrict__ zbuf, int use_f16,
    float* __restrict__ ssum, float* __restrict__ ssumsq)
{
    __shared__ int   s_nodes[NPB][4];
    __shared__ float s_g[NPB][4];
    __shared__ float s_m0[NPB];
    __shared__ float s_redA[4][256];
    __shared__ float s_redB[4][256];
    int tid = threadIdx.x;
    int g = tid >> 6, lane = tid & 63;
    int base = blockIdx.x * NPB;      // 30000 = 2000*15 exactly
    if (tid < NPB) {
        int node = base + tid;
        float fr = 0.f;
#pragma unroll
        for (int t = 0; t < 16; t++) { float v = subH[node * 16 + t]; fr += v * v; }
        // A = -i * H * 1e-4/||H||_F  (eigen- and norm-clamps provably always fire
        // and their scalar factors cancel; Taylor >=2nd order terms are <=5e-9)
        float coef = 1e-4f * rsqrtf(fr);
#pragma unroll
        for (int s = 0; s < 4; s++) {
            s_g[tid][s]     = coef * subH[node * 16 + s] * sub_mask[node * 4 + s];
            s_nodes[tid][s] = sub_nodes[node * 4 + s];
        }
        s_m0[tid] = sub_mask[node * 4];
    }
    __syncthreads();
    float esc = *escp;
    float lsum[4] = {0.f, 0.f, 0.f, 0.f};
    float lsq[4]  = {0.f, 0.f, 0.f, 0.f};
    for (int j = g; j < NPB; j += 4) {
        int node = base + j;
        f16x8 hv[4];
#pragma unroll
        for (int s = 0; s < 4; s++)
            hv[s] = *reinterpret_cast<const f16x8*>(h + s_nodes[j][s] * 512 + lane * 8);
        float4 x4 = *reinterpret_cast<const float4*>(x + node * NC + lane * 4);
        float xr[4] = {x4.x, x4.y, x4.z, x4.w};
        float G[4] = {s_g[j][0], s_g[j][1], s_g[j][2], s_g[j][3]};
        float m0 = s_m0[j];
        f16x8 zo;
        float or4[4], oi4[4];
#pragma unroll
        for (int e = 0; e < 4; e++) {
            float hr0 = (float)hv[0][2 * e], hi0 = (float)hv[0][2 * e + 1];
            float er = m0 * hr0, ei = m0 * hi0;     // identity (self) term
#pragma unroll
            for (int s = 0; s < 4; s++) {
                float hr = (float)hv[s][2 * e], hi = (float)hv[s][2 * e + 1];
                er = fmaf(G[s], hi, er);            // -i*g*(hr+i*hi)
                ei = fmaf(-G[s], hr, ei);
            }
            float outr = fmaf(esc, er, xr[e]);
            float outi = esc * ei;
            or4[e] = outr; oi4[e] = outi;
            zo[2 * e] = (_Float16)outr; zo[2 * e + 1] = (_Float16)outi;
            float mag = sqrtf(fmaf(outr, outr, fmaf(outi, outi, 1e-5f)));
            mag = fminf(fmaxf(mag, 1e-5f), 1000.f);
            lsum[e] += mag;
            lsq[e] = fmaf(mag, mag, lsq[e]);
        }
        if (use_f16) {
            *reinterpret_cast<f16x8*>(zbuf + node * 512 + lane * 8) = zo;
        } else {
            *reinterpret_cast<float4*>(outz + node * 512 + lane * 4) =
                make_float4(or4[0], or4[1], or4[2], or4[3]);
            *reinterpret_cast<float4*>(outz + node * 512 + 256 + lane * 4) =
                make_float4(oi4[0], oi4[1], oi4[2], oi4[3]);
        }
    }
#pragma unroll
    for (int e = 0; e < 4; e++) {
        s_redA[g][lane * 4 + e] = lsum[e];
        s_redB[g][lane * 4 + e] = lsq[e];
    }
    __syncthreads();
    float a = s_redA[0][tid] + s_redA[1][tid] + s_redA[2][tid] + s_redA[3][tid];
    float b = s_redB[0][tid] + s_redB[1][tid] + s_redB[2][tid] + s_redB[3][tid];
    atomicAdd(&ssum[tid], a);      // tid == channel; 2000 adds per address
    atomicAdd(&ssumsq[tid], b);
}

// ---- layernorm + phase + leaky crelu; stats affine recomputed inline ----
__global__ __launch_bounds__(256) void k_norm(
    float* __restrict__ out, const _Float16* __restrict__ zbuf, int use_f16,
    const float* __restrict__ ssum, const float* __restrict__ ssumsq,
    const float* __restrict__ lnw, const float* __restrict__ lnb)
{
    int tid = threadIdx.x;
    int node = blockIdx.x * 4 + (tid >> 6);        // 7500 blocks
    int c0 = (tid & 63) * 4;
    float re[4], im[4];
    if (use_f16) {
        f16x8 z = *reinterpret_cast<const f16x8*>(zbuf + node * 512 + c0 * 2);
#pragma unroll
        for (int e = 0; e < 4; e++) { re[e] = (float)z[2 * e]; im[e] = (float)z[2 * e + 1]; }
    } else {
        float4 r4 = *reinterpret_cast<const float4*>(out + node * 512 + c0);
        float4 i4 = *reinterpret_cast<const float4*>(out + node * 512 + 256 + c0);
        re[0] = r4.x; re[1] = r4.y; re[2] = r4.z; re[3] = r4.w;
        im[0] = i4.x; im[1] = i4.y; im[2] = i4.z; im[3] = i4.w;
    }
    float4 s4 = *reinterpret_cast<const float4*>(ssum + c0);
    float4 q4 = *reinterpret_cast<const float4*>(ssumsq + c0);
    float4 w4 = *reinterpret_cast<const float4*>(lnw + c0);
    float4 lb4 = *reinterpret_cast<const float4*>(lnb + c0);
    float S[4] = {s4.x, s4.y, s4.z, s4.w};
    float Q[4] = {q4.x, q4.y, q4.z, q4.w};
    float W[4] = {w4.x, w4.y, w4.z, w4.w};
    float L[4] = {lb4.x, lb4.y, lb4.z, lb4.w};
    const float invN = 1.0f / (float)N_NODES;
    float orr[4], oii[4];
#pragma unroll
    for (int e = 0; e < 4; e++) {
        float mean = S[e] * invN;
        float var = fmaxf(Q[e] * invN - mean * mean, 0.f);
        float denom = sqrtf(var + 1e-5f) + 1e-5f;
        float A = fabsf(W[e]) / denom;
        float Bc = L[e] - mean * A;
        float r = re[e], i = im[e];
        float mag = sqrtf(fmaf(r, r, fmaf(i, i, 1e-5f)));
        mag = fminf(fmaxf(mag, 1e-5f), 1000.f);
        float sm = fmaf(mag, A, Bc);
        sm = fminf(fmaxf(sm, 1e-5f), 10.0f);
        float px = fminf(fmaxf(r, -1e6f), 1e6f) + 1e-10f;
        float py = fminf(fmaxf(i, -1e6f), 1e6f);
        float r2 = fmaf(px, px, py * py);
        float inv = rsqrtf(r2);
        float zr = sm * px * inv, zi = sm * py * inv;
        zr = fminf(fmaxf(zr, -5.f), 5.f);
        zi = fminf(fmaxf(zi, -5.f), 5.f);
        orr[e] = zr > 0.f ? zr : 0.01f * zr;
        oii[e] = zi > 0.f ? zi : 0.01f * zi;
    }
    *reinterpret_cast<float4*>(out + node * 512 + c0) =
        make_float4(orr[0], orr[1], orr[2], orr[3]);
    *reinterpret_cast<float4*>(out + node * 512 + 256 + c0) =
        make_float4(oii[0], oii[1], oii[2], oii[3]);
}

extern "C" void kernel_launch(void* const* d_in, const int* in_sizes, int n_in,
                              void* d_out, int out_size, void* d_ws, size_t ws_size,
                              hipStream_t stream) {
    const float* x        = (const float*)d_in[0];
    // d_in[1] edge_index: unused (sub_nodes/sub_mask/sub_H are precomputed)
    const int*   sub_nodes = (const int*)d_in[2];
    const float* sub_mask  = (const float*)d_in[3];
    const float* subH      = (const float*)d_in[4];
    const float* wr  = (const float*)d_in[5];
    const float* wi  = (const float*)d_in[6];
    const float* br  = (const float*)d_in[7];
    const float* bi  = (const float*)d_in[8];
    const float* lnw = (const float*)d_in[9];
    const float* lnb = (const float*)d_in[10];
    const float* esc = (const float*)d_in[11];
    float* out = (float*)d_out;

    char* ws = (char*)d_ws;
    const size_t XB_OFF   = 0;                    // 30000*256*2  = 15,360,000
    const size_t WB_OFF   = 15360000;             // 512*256*2    =    262,144
    const size_t H_OFF    = 15622144;             // 30000*512*2  = 30,720,000
    const size_t STAT_OFF = 46342144;             // 4 * 1024
    const size_t ZB_OFF   = 46346240;             // 30000*512*2  = 30,720,000 (optional)
    const size_t WS_NEED_F16 = ZB_OFF + 30720000; // 77,066,240
    _Float16* xb = (_Float16*)(ws + XB_OFF);
    _Float16* Wb = (_Float16*)(ws + WB_OFF);
    _Float16* h  = (_Float16*)(ws + H_OFF);
    float* ssum   = (float*)(ws + STAT_OFF);
    float* ssumsq = (float*)(ws + STAT_OFF + 1024);
    _Float16* zbuf = (_Float16*)(ws + ZB_OFF);
    int use_f16 = (ws_size >= WS_NEED_F16) ? 1 : 0;

    hipMemsetAsync(ssum, 0, 2048, stream);
    hipLaunchKernelGGL(k_conv_x, dim3(7500), dim3(256), 0, stream, x, xb);
    hipLaunchKernelGGL(k_conv_w, dim3(128), dim3(256), 0, stream, wr, wi, Wb);
    hipLaunchKernelGGL(k_gemm, dim3(235 * 4), dim3(256), 0, stream, xb, Wb, br, bi, h);
    hipLaunchKernelGGL(k_evolve, dim3(2000), dim3(256), 0, stream,
                       x, sub_nodes, sub_mask, subH, h, esc, out, zbuf, use_f16,
                       ssum, ssumsq);
    hipLaunchKernelGGL(k_norm, dim3(7500), dim3(256), 0, stream,
                       out, zbuf, use_f16, ssum, ssumsq, lnw, lnb);
}

// Round 2
// 200.107 us; speedup vs baseline: 1.1452x; 1.1452x over previous
//
#include <hip/hip_runtime.h>
#include <stdint.h>

#define N_NODES 30000
#define NC 256

typedef _Float16 f16x8 __attribute__((ext_vector_type(8)));
typedef _Float16 f16x4 __attribute__((ext_vector_type(4)));
typedef _Float16 f16x2 __attribute__((ext_vector_type(2)));
typedef float f32x4 __attribute__((ext_vector_type(4)));

// ---- convert x (with clip +-10) to f16 ----
__global__ void k_conv_x(const float* __restrict__ x, _Float16* __restrict__ xb) {
    int i = (blockIdx.x * 256 + threadIdx.x) * 4;   // total 7,680,000 -> 7500 blocks
    float4 v = *reinterpret_cast<const float4*>(x + i);
    f16x4 o;
    o[0] = (_Float16)fminf(fmaxf(v.x, -10.f), 10.f);
    o[1] = (_Float16)fminf(fmaxf(v.y, -10.f), 10.f);
    o[2] = (_Float16)fminf(fmaxf(v.z, -10.f), 10.f);
    o[3] = (_Float16)fminf(fmaxf(v.w, -10.f), 10.f);
    *reinterpret_cast<f16x4*>(xb + i) = o;
}

// ---- convert W = [w_real; w_imag] ([512][256]) to f16 ----
__global__ void k_conv_w(const float* __restrict__ wr, const float* __restrict__ wi,
                         _Float16* __restrict__ Wb) {
    int i = (blockIdx.x * 256 + threadIdx.x) * 4;   // total 131,072 -> 128 blocks
    const float* src = (i < NC * NC) ? (wr + i) : (wi + (i - NC * NC));
    float4 v = *reinterpret_cast<const float4*>(src);
    f16x4 o;
    o[0] = (_Float16)v.x; o[1] = (_Float16)v.y;
    o[2] = (_Float16)v.z; o[3] = (_Float16)v.w;
    *reinterpret_cast<f16x4*>(Wb + i) = o;
}

// ---- prep: per-node complex coefficient P_s = esc*1e-4*subH[0][s]*mask[s]/||H||_F
// (eigen/norm clamps provably always fire; mask[0]==1 so the identity-term
// coefficient is just esc). Fully parallel: removes evolve's serial prologue.
__global__ void k_prep(const float* __restrict__ subH, const float* __restrict__ sub_mask,
                       const float* __restrict__ escp, float* __restrict__ c4) {
    int node = blockIdx.x * 256 + threadIdx.x;      // 118 blocks
    if (node >= N_NODES) return;
    float esc = *escp;
    const float4* Hp = reinterpret_cast<const float4*>(subH + node * 16);
    float4 r0 = Hp[0], r1 = Hp[1], r2 = Hp[2], r3 = Hp[3];
    float fr = r0.x * r0.x + r0.y * r0.y + r0.z * r0.z + r0.w * r0.w
             + r1.x * r1.x + r1.y * r1.y + r1.z * r1.z + r1.w * r1.w
             + r2.x * r2.x + r2.y * r2.y + r2.z * r2.z + r2.w * r2.w
             + r3.x * r3.x + r3.y * r3.y + r3.z * r3.z + r3.w * r3.w;
    float coef = 1e-4f * rsqrtf(fr) * esc;
    float4 m = *reinterpret_cast<const float4*>(sub_mask + node * 4);
    float4 o;
    o.x = coef * r0.x * m.x;
    o.y = coef * r0.y * m.y;
    o.z = coef * r0.z * m.z;
    o.w = coef * r0.w * m.w;
    *reinterpret_cast<float4*>(c4 + node * 4) = o;
}

// ---- GEMM v3 (reverted to the 211.8us config): A register-resident full K ----
__global__ __launch_bounds__(256, 2) void k_gemm(
    const _Float16* __restrict__ A, const _Float16* __restrict__ B,
    const float* __restrict__ br, const float* __restrict__ bi,
    _Float16* __restrict__ H)
{
    int bid = blockIdx.x;
    int bm = bid >> 1, cs = bid & 1;          // 235 x 2 blocks
    int tid = threadIdx.x;
    int lane = tid & 63, wave = tid >> 6;
    int quad = lane >> 4, l16 = lane & 15;
    int wm = wave >> 1, wn = wave & 1;        // wm: row half, wn: re/im
    int row0 = bm * 128 + wm * 64;

    f16x8 af[4][8];
#pragma unroll
    for (int mi = 0; mi < 4; mi++) {
        int r = row0 + mi * 16 + l16;
        if (r >= N_NODES) r = N_NODES - 1;    // clamp: garbage rows never stored
        const _Float16* ap = A + r * NC + quad * 8;
#pragma unroll
        for (int kc = 0; kc < 8; kc++)
            af[mi][kc] = *reinterpret_cast<const f16x8*>(ap + kc * 32);
    }

    const float* bias_p = wn ? bi : br;
#pragma unroll
    for (int cn = 0; cn < 2; cn++) {
        const _Float16* bbase = B + ((wn ? 256 : 0) + cs * 128 + cn * 64 + l16) * NC
                                  + quad * 8;
        f16x8 bb[2][4];
#pragma unroll
        for (int ni = 0; ni < 4; ni++)
            bb[0][ni] = *reinterpret_cast<const f16x8*>(bbase + ni * 16 * NC);
        f32x4 acc[4][4] = {};
#pragma unroll
        for (int kc = 0; kc < 8; kc++) {
            int cur = kc & 1, nxt = cur ^ 1;
            if (kc < 7) {
#pragma unroll
                for (int ni = 0; ni < 4; ni++)
                    bb[nxt][ni] = *reinterpret_cast<const f16x8*>(
                        bbase + ni * 16 * NC + (kc + 1) * 32);
            }
#pragma unroll
            for (int mi = 0; mi < 4; mi++)
#pragma unroll
                for (int ni = 0; ni < 4; ni++)
                    acc[mi][ni] = __builtin_amdgcn_mfma_f32_16x16x32_f16(
                        af[mi][kc], bb[cur][ni], acc[mi][ni], 0, 0, 0);
        }
#pragma unroll
        for (int ni = 0; ni < 4; ni++) {
            int c = cs * 128 + cn * 64 + ni * 16 + l16;
            float bias = bias_p[c];
            int cc = 2 * c + wn;
#pragma unroll
            for (int mi = 0; mi < 4; mi++) {
                int rowb = row0 + mi * 16 + quad * 4;
#pragma unroll
                for (int r = 0; r < 4; r++) {
                    int row = rowb + r;
                    if (row < N_NODES)
                        H[row * 512 + cc] = (_Float16)(acc[mi][ni][r] + bias);
                }
            }
        }
    }
}

// ---- evolve v4: NPB=60 / 512 threads (8 groups) / 500 blocks; coef precomputed
// by k_prep; 2-deep software pipeline on the j-loop.
// R1 evidence: T = nblocks*13.9ns + 33.4us -> halve block count at constant wave
// count (4000) and strip the prologue; pipeline hides the L3-gather latency that
// left both VALU (13%) and HBM (22%) idle.
#define NPB 60
#define NGRP 8
__global__ __launch_bounds__(512) void k_evolve(
    const float* __restrict__ x, const int* __restrict__ sub_nodes,
    const float* __restrict__ c4, const _Float16* __restrict__ h,
    const float* __restrict__ escp,
    float* __restrict__ outz, _Float16* __restrict__ zbuf, int use_f16,
    float* __restrict__ ssum, float* __restrict__ ssumsq)
{
    __shared__ int   s_nodes[NPB][4];
    __shared__ float s_P[NPB][4];
    __shared__ float s_redA[NGRP][256];
    __shared__ float s_redB[NGRP][256];
    int tid = threadIdx.x;
    int g = tid >> 6, lane = tid & 63;
    int base = blockIdx.x * NPB;      // 30000 = 500*60 exactly
    if (tid < NPB) {
        int node = base + tid;
        *reinterpret_cast<float4*>(&s_P[tid][0]) =
            *reinterpret_cast<const float4*>(c4 + node * 4);
        *reinterpret_cast<int4*>(&s_nodes[tid][0]) =
            *reinterpret_cast<const int4*>(sub_nodes + node * 4);
    }
    __syncthreads();
    float esc = *escp;
    float lsum[4] = {0.f, 0.f, 0.f, 0.f};
    float lsq[4]  = {0.f, 0.f, 0.f, 0.f};

    f16x8 hvA[4];
    float4 xA;
    int j = g;
#pragma unroll
    for (int s = 0; s < 4; s++)
        hvA[s] = *reinterpret_cast<const f16x8*>(h + s_nodes[j][s] * 512 + lane * 8);
    xA = *reinterpret_cast<const float4*>(x + (base + j) * NC + lane * 4);

    for (;;) {
        int jn = j + NGRP;
        bool more = jn < NPB;
        f16x8 hvB[4];
        float4 xB;
        if (more) {
#pragma unroll
            for (int s = 0; s < 4; s++)
                hvB[s] = *reinterpret_cast<const f16x8*>(
                    h + s_nodes[jn][s] * 512 + lane * 8);
            xB = *reinterpret_cast<const float4*>(x + (base + jn) * NC + lane * 4);
        }
        // ---- compute node j from hvA/xA ----
        {
            int node = base + j;
            float P0 = s_P[j][0], P1 = s_P[j][1], P2 = s_P[j][2], P3 = s_P[j][3];
            float xr[4] = {xA.x, xA.y, xA.z, xA.w};
            f16x8 zo;
            float or4[4], oi4[4];
#pragma unroll
            for (int e = 0; e < 4; e++) {
                float hr0 = (float)hvA[0][2 * e], hi0 = (float)hvA[0][2 * e + 1];
                float hr1 = (float)hvA[1][2 * e], hi1 = (float)hvA[1][2 * e + 1];
                float hr2 = (float)hvA[2][2 * e], hi2 = (float)hvA[2][2 * e + 1];
                float hr3 = (float)hvA[3][2 * e], hi3 = (float)hvA[3][2 * e + 1];
                float er = esc * hr0;             // identity (self) term, m0==1
                float ei = esc * hi0;
                er = fmaf(P0, hi0, er); ei = fmaf(-P0, hr0, ei);
                er = fmaf(P1, hi1, er); ei = fmaf(-P1, hr1, ei);
                er = fmaf(P2, hi2, er); ei = fmaf(-P2, hr2, ei);
                er = fmaf(P3, hi3, er); ei = fmaf(-P3, hr3, ei);
                float outr = er + xr[e];
                float outi = ei;
                or4[e] = outr; oi4[e] = outi;
                zo[2 * e] = (_Float16)outr; zo[2 * e + 1] = (_Float16)outi;
                float mag = sqrtf(fmaf(outr, outr, fmaf(outi, outi, 1e-5f)));
                mag = fminf(fmaxf(mag, 1e-5f), 1000.f);
                lsum[e] += mag;
                lsq[e] = fmaf(mag, mag, lsq[e]);
            }
            if (use_f16) {
                *reinterpret_cast<f16x8*>(zbuf + node * 512 + lane * 8) = zo;
            } else {
                *reinterpret_cast<float4*>(outz + node * 512 + lane * 4) =
                    make_float4(or4[0], or4[1], or4[2], or4[3]);
                *reinterpret_cast<float4*>(outz + node * 512 + 256 + lane * 4) =
                    make_float4(oi4[0], oi4[1], oi4[2], oi4[3]);
            }
        }
        if (!more) break;
#pragma unroll
        for (int s = 0; s < 4; s++) hvA[s] = hvB[s];
        xA = xB;
        j = jn;
    }
#pragma unroll
    for (int e = 0; e < 4; e++) {
        s_redA[g][lane * 4 + e] = lsum[e];
        s_redB[g][lane * 4 + e] = lsq[e];
    }
    __syncthreads();
    if (tid < 256) {
        float a = 0.f;
#pragma unroll
        for (int q = 0; q < NGRP; q++) a += s_redA[q][tid];
        atomicAdd(&ssum[tid], a);          // tid == channel; 500 adds per address
    } else {
        int t = tid - 256;
        float b = 0.f;
#pragma unroll
        for (int q = 0; q < NGRP; q++) b += s_redB[q][t];
        atomicAdd(&ssumsq[t], b);
    }
}

// ---- layernorm + phase + leaky crelu; stats affine recomputed inline ----
__global__ __launch_bounds__(256) void k_norm(
    float* __restrict__ out, const _Float16* __restrict__ zbuf, int use_f16,
    const float* __restrict__ ssum, const float* __restrict__ ssumsq,
    const float* __restrict__ lnw, const float* __restrict__ lnb)
{
    int tid = threadIdx.x;
    int node = blockIdx.x * 4 + (tid >> 6);        // 7500 blocks
    int c0 = (tid & 63) * 4;
    float re[4], im[4];
    if (use_f16) {
        f16x8 z = *reinterpret_cast<const f16x8*>(zbuf + node * 512 + c0 * 2);
#pragma unroll
        for (int e = 0; e < 4; e++) { re[e] = (float)z[2 * e]; im[e] = (float)z[2 * e + 1]; }
    } else {
        float4 r4 = *reinterpret_cast<const float4*>(out + node * 512 + c0);
        float4 i4 = *reinterpret_cast<const float4*>(out + node * 512 + 256 + c0);
        re[0] = r4.x; re[1] = r4.y; re[2] = r4.z; re[3] = r4.w;
        im[0] = i4.x; im[1] = i4.y; im[2] = i4.z; im[3] = i4.w;
    }
    float4 s4 = *reinterpret_cast<const float4*>(ssum + c0);
    float4 q4 = *reinterpret_cast<const float4*>(ssumsq + c0);
    float4 w4 = *reinterpret_cast<const float4*>(lnw + c0);
    float4 lb4 = *reinterpret_cast<const float4*>(lnb + c0);
    float S[4] = {s4.x, s4.y, s4.z, s4.w};
    float Q[4] = {q4.x, q4.y, q4.z, q4.w};
    float W[4] = {w4.x, w4.y, w4.z, w4.w};
    float L[4] = {lb4.x, lb4.y, lb4.z, lb4.w};
    const float invN = 1.0f / (float)N_NODES;
    float orr[4], oii[4];
#pragma unroll
    for (int e = 0; e < 4; e++) {
        float mean = S[e] * invN;
        float var = fmaxf(Q[e] * invN - mean * mean, 0.f);
        float denom = sqrtf(var + 1e-5f) + 1e-5f;
        float A = fabsf(W[e]) / denom;
        float Bc = L[e] - mean * A;
        float r = re[e], i = im[e];
        float mag = sqrtf(fmaf(r, r, fmaf(i, i, 1e-5f)));
        mag = fminf(fmaxf(mag, 1e-5f), 1000.f);
        float sm = fmaf(mag, A, Bc);
        sm = fminf(fmaxf(sm, 1e-5f), 10.0f);
        float px = fminf(fmaxf(r, -1e6f), 1e6f) + 1e-10f;
        float py = fminf(fmaxf(i, -1e6f), 1e6f);
        float r2 = fmaf(px, px, py * py);
        float inv = rsqrtf(r2);
        float zr = sm * px * inv, zi = sm * py * inv;
        zr = fminf(fmaxf(zr, -5.f), 5.f);
        zi = fminf(fmaxf(zi, -5.f), 5.f);
        orr[e] = zr > 0.f ? zr : 0.01f * zr;
        oii[e] = zi > 0.f ? zi : 0.01f * zi;
    }
    *reinterpret_cast<float4*>(out + node * 512 + c0) =
        make_float4(orr[0], orr[1], orr[2], orr[3]);
    *reinterpret_cast<float4*>(out + node * 512 + 256 + c0) =
        make_float4(oii[0], oii[1], oii[2], oii[3]);
}

extern "C" void kernel_launch(void* const* d_in, const int* in_sizes, int n_in,
                              void* d_out, int out_size, void* d_ws, size_t ws_size,
                              hipStream_t stream) {
    const float* x        = (const float*)d_in[0];
    // d_in[1] edge_index: unused (sub_nodes/sub_mask/sub_H are precomputed)
    const int*   sub_nodes = (const int*)d_in[2];
    const float* sub_mask  = (const float*)d_in[3];
    const float* subH      = (const float*)d_in[4];
    const float* wr  = (const float*)d_in[5];
    const float* wi  = (const float*)d_in[6];
    const float* br  = (const float*)d_in[7];
    const float* bi  = (const float*)d_in[8];
    const float* lnw = (const float*)d_in[9];
    const float* lnb = (const float*)d_in[10];
    const float* esc = (const float*)d_in[11];
    float* out = (float*)d_out;

    char* ws = (char*)d_ws;
    const size_t XB_OFF   = 0;                    // 30000*256*2  = 15,360,000
    const size_t WB_OFF   = 15360000;             // 512*256*2    =    262,144
    const size_t H_OFF    = 15622144;             // 30000*512*2  = 30,720,000
    const size_t STAT_OFF = 46342144;             // 2 * 1024 (alloc 4096)
    const size_t C4_OFF   = 46346240;             // 30000*16     =    480,000
    const size_t ZB_OFF   = 46826240;             // 30000*512*2  = 30,720,000 (optional)
    const size_t WS_NEED_F16 = ZB_OFF + 30720000; // 77,546,240
    _Float16* xb = (_Float16*)(ws + XB_OFF);
    _Float16* Wb = (_Float16*)(ws + WB_OFF);
    _Float16* h  = (_Float16*)(ws + H_OFF);
    float* ssum   = (float*)(ws + STAT_OFF);
    float* ssumsq = (float*)(ws + STAT_OFF + 1024);
    float* c4     = (float*)(ws + C4_OFF);
    _Float16* zbuf = (_Float16*)(ws + ZB_OFF);
    int use_f16 = (ws_size >= WS_NEED_F16) ? 1 : 0;

    hipMemsetAsync(ssum, 0, 2048, stream);
    hipLaunchKernelGGL(k_conv_x, dim3(7500), dim3(256), 0, stream, x, xb);
    hipLaunchKernelGGL(k_conv_w, dim3(128), dim3(256), 0, stream, wr, wi, Wb);
    hipLaunchKernelGGL(k_prep, dim3(118), dim3(256), 0, stream,
                       subH, sub_mask, esc, c4);
    hipLaunchKernelGGL(k_gemm, dim3(235 * 2), dim3(256), 0, stream, xb, Wb, br, bi, h);
    hipLaunchKernelGGL(k_evolve, dim3(500), dim3(512), 0, stream,
                       x, sub_nodes, c4, h, esc, out, zbuf, use_f16,
                       ssum, ssumsq);
    hipLaunchKernelGGL(k_norm, dim3(7500), dim3(256), 0, stream,
                       out, zbuf, use_f16, ssum, ssumsq, lnw, lnb);
}